// Round 6
// baseline (161.927 us; speedup 1.0000x reference)
//
#include <hip/hip_runtime.h>

typedef _Float16 half8 __attribute__((ext_vector_type(8)));
typedef float f32x16 __attribute__((ext_vector_type(16)));

#define WD 7
#define NPAD 128
#define KDIM 8330
#define KT 8704          // 8 * KSLICE; wt rows zero-padded past 8330
#define BSZ 4096
#define SPLITK 8
#define KSLICE 1088      // 17 * 64
#define NITER 17         // uniform for all splits (split 7 tail tiles are zeros)
#define BM 64
#define BK 64
#define XROWB 272        // 256B row + 16B pad (16B-aligned rows, ~4-way max conflict)
#define XHALF (32 * XROWB)        // one 32-row buffer = 8704 B
#define XLDS_TOTAL (6 * XHALF)    // 2 row-halves x 3 buffers = 52,224 B

// ws layout (bytes)
static constexpr size_t OFF_WT   = 0;                              // _Float16[2][128][KT]
static constexpr size_t WT_BYTES = (size_t)2 * NPAD * KT * 2;      // 4,456,448
static constexpr size_t OFF_BIAS = WT_BYTES;                       // 128 floats
static constexpr size_t OFF_PART = OFF_BIAS + 512;                 // [SPLITK][BSZ][NPAD] f32
// total ~21.2 MB

static __device__ const int KIDX[5][4] = {
    {0, 1, 3, 4}, {7, 8, 9, 10}, {5, 6, 11, 12}, {11, 12, 13, 14}, {15, 16, 15, 16}};
static __device__ const unsigned long long OBASE[5] = {0ull, 401408ull, 802816ull, 1204224ull, 1605632ull};

__device__ __forceinline__ unsigned pk16(_Float16 a, _Float16 b) {
  return (unsigned)__builtin_bit_cast(unsigned short, a) |
         ((unsigned)__builtin_bit_cast(unsigned short, b) << 16);
}

__device__ __forceinline__ void gload_lds4(const void* g, void* l) {
  __builtin_amdgcn_global_load_lds((const __attribute__((address_space(1))) unsigned int*)g,
                                   (__attribute__((address_space(3))) unsigned int*)l, 4, 0, 0);
}

// ---------------- pack: W -> transposed fp16 hi/lo wt[comp][n][k], bias
__global__ __launch_bounds__(256) void pack_kernel(
    const float* __restrict__ Wh, const float* __restrict__ bh,
    const float* __restrict__ Wa, const float* __restrict__ ba,
    const float* __restrict__ Wu, const float* __restrict__ bu,
    const float* __restrict__ Wl_, const float* __restrict__ bl,
    const float* __restrict__ Wf, const float* __restrict__ bf,
    char* __restrict__ wsb) {
  _Float16* wt_h = (_Float16*)(wsb + OFF_WT);
  _Float16* wt_l = wt_h + (size_t)NPAD * KT;
  float* bias = (float*)(wsb + OFF_BIAS);
  __shared__ _Float16 sh[64][128];
  __shared__ _Float16 sl[64][128];
  const int k0 = blockIdx.x * 64;
  const int tid = threadIdx.x;

#pragma unroll
  for (int jj = 0; jj < 32; ++jj) {
    int idx = tid + 256 * jj;
    int kk = idx >> 7, n = idx & 127;
    int k = k0 + kk;
    float w = 0.f;
    if (k < KDIM) {
      if      (n < 28)  w = Wh [k * 28 + n];
      else if (n < 56)  w = Wa [k * 28 + (n - 28)];
      else if (n < 84)  w = Wu [k * 28 + (n - 56)];
      else if (n < 112) w = Wl_[k * 28 + (n - 84)];
      else if (n < 126) w = Wf [k * 14 + (n - 112)];
    }
    _Float16 h = (_Float16)w;
    _Float16 l = (_Float16)((w - (float)h) * 2048.0f);
    sh[kk][n] = h;
    sl[kk][n] = l;
  }
  if (blockIdx.x == 0 && tid < NPAD) {
    int n = tid;
    float v = 0.f;
    if      (n < 28)  v = bh[n];
    else if (n < 56)  v = ba[n - 28];
    else if (n < 84)  v = bu[n - 56];
    else if (n < 112) v = bl[n - 84];
    else if (n < 126) v = bf[n - 112];
    bias[n] = v;
  }
  __syncthreads();
  const int n = tid >> 1;
  const int kc = (tid & 1) * 32;
  size_t ob = (size_t)n * KT + k0 + kc;
#pragma unroll
  for (int c = 0; c < 4; ++c) {
    uint4 qh, ql;
    qh.x = pk16(sh[kc + c * 8 + 0][n], sh[kc + c * 8 + 1][n]);
    qh.y = pk16(sh[kc + c * 8 + 2][n], sh[kc + c * 8 + 3][n]);
    qh.z = pk16(sh[kc + c * 8 + 4][n], sh[kc + c * 8 + 5][n]);
    qh.w = pk16(sh[kc + c * 8 + 6][n], sh[kc + c * 8 + 7][n]);
    ql.x = pk16(sl[kc + c * 8 + 0][n], sl[kc + c * 8 + 1][n]);
    ql.y = pk16(sl[kc + c * 8 + 2][n], sl[kc + c * 8 + 3][n]);
    ql.z = pk16(sl[kc + c * 8 + 4][n], sl[kc + c * 8 + 5][n]);
    ql.w = pk16(sl[kc + c * 8 + 6][n], sl[kc + c * 8 + 7][n]);
    *(uint4*)(wt_h + ob + c * 8) = qh;
    *(uint4*)(wt_l + ob + c * 8) = ql;
  }
}

struct BSet { half8 h[2][4]; half8 l[2][4]; };  // 128 VGPR across 2 sets

// ---------------- GEMM: partial[s] = x[:, slice] @ W[slice, :]
// 4 waves = 2 row-halves x 2 col-halves. x staged by col-wave 0 of each half
// into a shared triple-buffered LDS half (DMA, counted vmcnt). B prefetched
// one tile ahead into regs BEFORE any newer DMA -> MFMA never waits fresh HBM.
__global__ __launch_bounds__(256, 2) void gemm_kernel(const float* __restrict__ x,
                                                      char* __restrict__ wsb) {
  extern __shared__ char xlds[];
  const _Float16* wt = (const _Float16*)(wsb + OFF_WT);
  float* partial = (float*)(wsb + OFF_PART);
  const int bid = blockIdx.x;
  const int split = bid & 7;                 // consecutive bids -> XCD round-robin
  const int row0 = (bid >> 3) * BM;
  const int ks = split * KSLICE;

  const int tid = threadIdx.x;
  const int lane = tid & 63;
  const int wid = tid >> 6;
  const int wm = wid & 1;                    // row half
  const int wn = wid >> 1;                   // col half

  // stage 32 rows of half wm into buffer `buf` (col-wave 0 only)
  auto stageX = [&](int buf, int t) {
    if (wn != 0) return;
    const int k0 = ks + t * BK;
    char* dst = xlds + (wm * 3 + buf) * XHALF;
    if (k0 + BK <= KDIM) {
#pragma unroll
      for (int r = 0; r < 32; ++r) {
        const float* src = x + (size_t)(row0 + wm * 32 + r) * KDIM + k0 + lane;
        gload_lds4((const void*)src, (void*)(dst + r * XROWB));
      }
    } else {
#pragma unroll
      for (int r = 0; r < 32; ++r) {
        int k = k0 + lane;
        float v = (k < KDIM) ? x[(size_t)(row0 + wm * 32 + r) * KDIM + k] : 0.f;
        *(float*)(dst + r * XROWB + lane * 4) = v;
      }
    }
  };

  auto loadB = [&](BSet& s, int t) {
    const _Float16* pk = wt + (size_t)(wn * 64 + (lane & 31)) * KT + ks + t * BK + (lane >> 5) * 8;
#pragma unroll
    for (int nt = 0; nt < 2; ++nt)
#pragma unroll
      for (int ksub = 0; ksub < 4; ++ksub) {
        s.h[nt][ksub] = *(const half8*)(pk + (size_t)nt * 32 * KT + ksub * 16);
        s.l[nt][ksub] = *(const half8*)(pk + (size_t)NPAD * KT + (size_t)nt * 32 * KT + ksub * 16);
      }
  };

  half8 ah[4], al[4];
  auto loadA = [&](int buf) {
    const char* ab = xlds + (wm * 3 + buf) * XHALF + (lane & 31) * XROWB + (lane >> 5) * 32;
#pragma unroll
    for (int ksub = 0; ksub < 4; ++ksub) {
      float4 f0 = *(const float4*)(ab + ksub * 64);
      float4 f1 = *(const float4*)(ab + ksub * 64 + 16);
      float f[8] = {f0.x, f0.y, f0.z, f0.w, f1.x, f1.y, f1.z, f1.w};
#pragma unroll
      for (int i = 0; i < 8; ++i) {
        _Float16 h = (_Float16)f[i];
        ah[ksub][i] = h;
        al[ksub][i] = (_Float16)((f[i] - (float)h) * 2048.0f);
      }
    }
  };

  f32x16 accA[2], accB[2];
#pragma unroll
  for (int nt = 0; nt < 2; ++nt) { accA[nt] = (f32x16)(0.f); accB[nt] = (f32x16)(0.f); }

  auto domfma = [&](const BSet& s) {
#pragma unroll
    for (int nt = 0; nt < 2; ++nt)
#pragma unroll
      for (int ksub = 0; ksub < 4; ++ksub) {
        accA[nt] = __builtin_amdgcn_mfma_f32_32x32x16_f16(ah[ksub], s.h[nt][ksub], accA[nt], 0, 0, 0);
        accB[nt] = __builtin_amdgcn_mfma_f32_32x32x16_f16(al[ksub], s.h[nt][ksub], accB[nt], 0, 0, 0);
        accB[nt] = __builtin_amdgcn_mfma_f32_32x32x16_f16(ah[ksub], s.l[nt][ksub], accB[nt], 0, 0, 0);
      }
  };

  BSet Bs0, Bs1;
  int b0 = 0, b1 = 1, b2 = 2;

  // prologue: invariant entering body(0): [B(0):16, stage(1):32] outstanding, stage(0) done
  stageX(b0, 0);
  stageX(b1, 1);
  loadB(Bs0, 0);
  asm volatile("s_waitcnt vmcnt(48) lgkmcnt(0)" ::: "memory");
  __builtin_amdgcn_s_barrier();

  for (int p = 0; p < 7; ++p) {
    const int t = 2 * p;
    // ---- body(t): uses Bs0, loads Bs1
    loadB(Bs1, t + 1);
    asm volatile("" ::: "memory");
    loadA(b0);
    domfma(Bs0);                      // compiler wait: vmcnt(48) -> B(t) ready; stage(t+1)+B(t+1) stay in flight
    __builtin_amdgcn_sched_barrier(0);
    stageX(b2, t + 2);
    asm volatile("s_waitcnt vmcnt(48) lgkmcnt(0)" ::: "memory");  // retire stage(t+1)
    __builtin_amdgcn_s_barrier();
    // ---- body(t+1): uses Bs1, loads Bs0
    loadB(Bs0, t + 2);
    asm volatile("" ::: "memory");
    loadA(b1);
    domfma(Bs1);
    __builtin_amdgcn_sched_barrier(0);
    stageX(b0, t + 3);
    asm volatile("s_waitcnt vmcnt(48) lgkmcnt(0)" ::: "memory");  // retire stage(t+2)
    __builtin_amdgcn_s_barrier();
    int tmp = b2; b2 = b1; b1 = b0; b0 = tmp;   // (b0,b1,b2) <- (b2,b0,b1)
  }

  // tail: tiles 14,15,16  (b0=buf(14%3)=2, b1=0, b2=1 by rotation)
  // t=14: uses Bs0, loads Bs1, stages 16
  loadB(Bs1, 15);
  asm volatile("" ::: "memory");
  loadA(b0);
  domfma(Bs0);
  __builtin_amdgcn_sched_barrier(0);
  stageX(b2, 16);
  asm volatile("s_waitcnt vmcnt(48) lgkmcnt(0)" ::: "memory");
  __builtin_amdgcn_s_barrier();
  // t=15: uses Bs1, loads Bs0, no stage; must retire stage(16)
  loadB(Bs0, 16);
  asm volatile("" ::: "memory");
  loadA(b1);
  domfma(Bs1);
  asm volatile("s_waitcnt vmcnt(16) lgkmcnt(0)" ::: "memory");
  __builtin_amdgcn_s_barrier();
  // t=16: uses Bs0
  loadA(b2);
  domfma(Bs0);

  float* pb = partial + (size_t)split * BSZ * NPAD;
  const int ahalf = lane >> 5;
#pragma unroll
  for (int nt = 0; nt < 2; ++nt)
#pragma unroll
    for (int r = 0; r < 16; ++r) {
      int row = row0 + wm * 32 + (r & 3) + 8 * (r >> 2) + 4 * ahalf;
      int col = wn * 64 + nt * 32 + (lane & 31);
      pb[(size_t)row * NPAD + col] = accA[nt][r] + accB[nt][r] * (1.0f / 2048.0f);
    }
}

// ---------------- fused reduce + epilogue
__device__ __forceinline__ void axis_mask(const float a[WD], int lo, int hi, float m[WD]) {
  float am[WD];
  float tot = 0.f;
#pragma unroll
  for (int c = 0; c < WD; ++c) { am[c] = (c >= lo) ? a[c] : 0.f; tot += am[c]; }
  float run = 0.f;
  float c1[WD];
#pragma unroll
  for (int c = 0; c < WD; ++c) {
    run += am[c] / tot;
    c1[c] = (run >= 0.3f) ? run : 0.f;
  }
  float tot2 = 0.f;
#pragma unroll
  for (int c = 0; c < WD; ++c) { am[c] = (c < hi) ? a[c] : 0.f; tot2 += am[c]; }
  run = 0.f;
#pragma unroll
  for (int c = 0; c < WD; ++c) {
    run += am[c] / tot2;
    float c2 = 1.f - run;
    c2 = (c2 >= 0.3f) ? c2 : 0.f;
    m[c] = c1[c] * c2;
  }
}

__global__ __launch_bounds__(256) void epi_kernel(const char* __restrict__ wsb,
                                                  const float* __restrict__ keypoint,
                                                  float* __restrict__ out) {
  int unit = blockIdx.x * 256 + threadIdx.x;
  if (unit >= BSZ * 5) return;
  int fam = unit >> 12;
  int b = unit & (BSZ - 1);
  const float* part = (const float*)(wsb + OFF_PART);
  const float* bias = (const float*)(wsb + OFF_BIAS);

  const int G = (fam == 4) ? 1 : 2;
  const int nk = (fam == 4) ? 2 : 4;
  const int base = fam * 28;
  const int ncol = (fam == 4) ? 14 : 28;

  float vv[28];
#pragma unroll
  for (int c = 0; c < 28; ++c)
    vv[c] = (c < ncol) ? part[(size_t)b * NPAD + base + c] : 0.f;
#pragma unroll
  for (int sp = 1; sp < SPLITK; ++sp) {
    const float* pr = part + ((size_t)sp * BSZ + b) * NPAD + base;
#pragma unroll
    for (int c = 0; c < 28; ++c)
      if (c < ncol) vv[c] += pr[c];
  }
#pragma unroll
  for (int c = 0; c < 28; ++c)
    if (c < ncol) vv[c] += bias[base + c];

  int mnx = 7, mxx = -1, mny = 7, mxy = -1;
  for (int i = 0; i < nk; ++i) {
    int kidx = KIDX[fam][i];
    float fx = keypoint[((size_t)b * 17 + kidx) * 2 + 0];
    float fy = keypoint[((size_t)b * 17 + kidx) * 2 + 1];
    int ix = (int)floorf(fx * 7.0f); ix = ix < 6 ? ix : 6;
    int iy = (int)floorf(fy * 7.0f); iy = iy < 6 ? iy : 6;
    mnx = min(mnx, ix); mxx = max(mxx, ix);
    mny = min(mny, iy); mxy = max(mxy, iy);
  }
  int lox = mnx - 1; if (lox < 0) lox = 0;
  int hix = mxx + 1; if (hix > 6) hix = 6;
  int loy = mny - 1; if (loy < 0) loy = 0;
  int hiy = mxy + 1; if (hiy > 6) hiy = 6;

  float xmg[2][WD], ymg[2][WD];
  float mx = 0.f;
#pragma unroll
  for (int g = 0; g < 2; ++g) {
    if (g < G) {
      const float* vg = vv + g * 14;
      float a0[WD], a1[WD];
#pragma unroll
      for (int c = 0; c < WD; ++c) {
        float s0 = vg[c], s1 = vg[c + 7];
        float mM = fmaxf(s0, s1);
        float e0 = expf(s0 - mM), e1 = expf(s1 - mM);
        float sum = e0 + e1;
        a0[c] = expf(e0 / sum);
        a1[c] = expf(e1 / sum);
      }
      axis_mask(a0, lox, hix, xmg[g]);
      axis_mask(a1, loy, hiy, ymg[g]);
      float mx_x = 0.f, mx_y = 0.f;
#pragma unroll
      for (int c = 0; c < WD; ++c) {
        mx_x = fmaxf(mx_x, xmg[g][c]);
        mx_y = fmaxf(mx_y, ymg[g][c]);
      }
      mx = fmaxf(mx, mx_y * mx_x);
    }
  }

  float d = mx + 1e-7f;
  float* op = out + OBASE[fam] + (size_t)b * (G * 49);
#pragma unroll
  for (int g = 0; g < 2; ++g) {
    if (g < G) {
#pragma unroll
      for (int y = 0; y < WD; ++y) {
        float yv = ymg[g][y];
#pragma unroll
        for (int xx = 0; xx < WD; ++xx) {
          op[g * 49 + y * 7 + xx] = (yv * xmg[g][xx]) / d;
        }
      }
    }
  }
}

extern "C" void kernel_launch(void* const* d_in, const int* in_sizes, int n_in,
                              void* d_out, int out_size, void* d_ws, size_t ws_size,
                              hipStream_t stream) {
  const float* x        = (const float*)d_in[0];
  const float* keypoint = (const float*)d_in[1];
  const float* Wh = (const float*)d_in[2];
  const float* bh = (const float*)d_in[3];
  const float* Wa = (const float*)d_in[4];
  const float* ba = (const float*)d_in[5];
  const float* Wu = (const float*)d_in[6];
  const float* bu = (const float*)d_in[7];
  const float* Wl = (const float*)d_in[8];
  const float* bl = (const float*)d_in[9];
  const float* Wf = (const float*)d_in[10];
  const float* bf = (const float*)d_in[11];
  float* out = (float*)d_out;
  char* wsb  = (char*)d_ws;

  (void)hipFuncSetAttribute(reinterpret_cast<const void*>(gemm_kernel),
                            hipFuncAttributeMaxDynamicSharedMemorySize, XLDS_TOTAL);

  hipLaunchKernelGGL(pack_kernel, dim3(KT / 64), dim3(256), 0, stream,
                     Wh, bh, Wa, ba, Wu, bu, Wl, bl, Wf, bf, wsb);
  hipLaunchKernelGGL(gemm_kernel, dim3((BSZ / BM) * SPLITK), dim3(256), XLDS_TOTAL, stream,
                     x, wsb);
  hipLaunchKernelGGL(epi_kernel, dim3(BSZ * 5 / 256), dim3(256), 0, stream,
                     wsb, keypoint, out);
}

// Round 7
// 149.137 us; speedup vs baseline: 1.0858x; 1.0858x over previous
//
#include <hip/hip_runtime.h>

typedef _Float16 half8 __attribute__((ext_vector_type(8)));
typedef float f32x16 __attribute__((ext_vector_type(16)));

#define WD 7
#define NPAD 128
#define KDIM 8330
#define KT 8704          // 8 * KSLICE; wt rows zero-padded past 8330
#define BSZ 4096
#define SPLITK 8
#define KSLICE 1088      // 34 * 32
#define NITER 34
#define BM 32
#define BK 32
#define XROWB 144        // 128B data + 16B pad -> 4-way max on A reads

// ws layout (bytes)
static constexpr size_t OFF_WT   = 0;                              // _Float16[2][128][KT]
static constexpr size_t WT_BYTES = (size_t)2 * NPAD * KT * 2;      // 4,456,448
static constexpr size_t OFF_BIAS = WT_BYTES;                       // 128 floats
static constexpr size_t OFF_PART = OFF_BIAS + 512;                 // [SPLITK][BSZ][NPAD] f32
// total ~21.2 MB

static __device__ const int KIDX[5][4] = {
    {0, 1, 3, 4}, {7, 8, 9, 10}, {5, 6, 11, 12}, {11, 12, 13, 14}, {15, 16, 15, 16}};
static __device__ const unsigned long long OBASE[5] = {0ull, 401408ull, 802816ull, 1204224ull, 1605632ull};

__device__ __forceinline__ unsigned pk16(_Float16 a, _Float16 b) {
  return (unsigned)__builtin_bit_cast(unsigned short, a) |
         ((unsigned)__builtin_bit_cast(unsigned short, b) << 16);
}

__device__ __forceinline__ void gload_lds16(const void* g, void* l) {
  __builtin_amdgcn_global_load_lds((const __attribute__((address_space(1))) unsigned int*)g,
                                   (__attribute__((address_space(3))) unsigned int*)l, 16, 0, 0);
}

// ---------------- pack: W -> transposed fp16 hi/lo wt[comp][n][k], bias
__global__ __launch_bounds__(256) void pack_kernel(
    const float* __restrict__ Wh, const float* __restrict__ bh,
    const float* __restrict__ Wa, const float* __restrict__ ba,
    const float* __restrict__ Wu, const float* __restrict__ bu,
    const float* __restrict__ Wl_, const float* __restrict__ bl,
    const float* __restrict__ Wf, const float* __restrict__ bf,
    char* __restrict__ wsb) {
  _Float16* wt_h = (_Float16*)(wsb + OFF_WT);
  _Float16* wt_l = wt_h + (size_t)NPAD * KT;
  float* bias = (float*)(wsb + OFF_BIAS);
  __shared__ _Float16 sh[64][128];
  __shared__ _Float16 sl[64][128];
  const int k0 = blockIdx.x * 64;
  const int tid = threadIdx.x;

#pragma unroll
  for (int jj = 0; jj < 32; ++jj) {
    int idx = tid + 256 * jj;
    int kk = idx >> 7, n = idx & 127;
    int k = k0 + kk;
    float w = 0.f;
    if (k < KDIM) {
      if      (n < 28)  w = Wh [k * 28 + n];
      else if (n < 56)  w = Wa [k * 28 + (n - 28)];
      else if (n < 84)  w = Wu [k * 28 + (n - 56)];
      else if (n < 112) w = Wl_[k * 28 + (n - 84)];
      else if (n < 126) w = Wf [k * 14 + (n - 112)];
    }
    _Float16 h = (_Float16)w;
    _Float16 l = (_Float16)((w - (float)h) * 2048.0f);
    sh[kk][n] = h;
    sl[kk][n] = l;
  }
  if (blockIdx.x == 0 && tid < NPAD) {
    int n = tid;
    float v = 0.f;
    if      (n < 28)  v = bh[n];
    else if (n < 56)  v = ba[n - 28];
    else if (n < 84)  v = bu[n - 56];
    else if (n < 112) v = bl[n - 84];
    else if (n < 126) v = bf[n - 112];
    bias[n] = v;
  }
  __syncthreads();
  const int n = tid >> 1;
  const int kc = (tid & 1) * 32;
  size_t ob = (size_t)n * KT + k0 + kc;
#pragma unroll
  for (int c = 0; c < 4; ++c) {
    uint4 qh, ql;
    qh.x = pk16(sh[kc + c * 8 + 0][n], sh[kc + c * 8 + 1][n]);
    qh.y = pk16(sh[kc + c * 8 + 2][n], sh[kc + c * 8 + 3][n]);
    qh.z = pk16(sh[kc + c * 8 + 4][n], sh[kc + c * 8 + 5][n]);
    qh.w = pk16(sh[kc + c * 8 + 6][n], sh[kc + c * 8 + 7][n]);
    ql.x = pk16(sl[kc + c * 8 + 0][n], sl[kc + c * 8 + 1][n]);
    ql.y = pk16(sl[kc + c * 8 + 2][n], sl[kc + c * 8 + 3][n]);
    ql.z = pk16(sl[kc + c * 8 + 4][n], sl[kc + c * 8 + 5][n]);
    ql.w = pk16(sl[kc + c * 8 + 6][n], sl[kc + c * 8 + 7][n]);
    *(uint4*)(wt_h + ob + c * 8) = qh;
    *(uint4*)(wt_l + ob + c * 8) = ql;
  }
}

// ---------------- GEMM: partial[s] = x[:, slice] @ W[slice, :]
// BM=32, BK=32, 4 waves (one 32-col quarter each), 4 blocks/CU.
// W: single-buffered LDS via global_load_lds (L2-resident, cheap vmcnt(0)).
// x: double-buffered LDS via regs (issue-early / write-late, T14).
__global__ __launch_bounds__(256, 4) void gemm_kernel(const float* __restrict__ x,
                                                      char* __restrict__ wsb) {
  const _Float16* wt = (const _Float16*)(wsb + OFF_WT);
  float* partial = (float*)(wsb + OFF_PART);
  const int bid = blockIdx.x;
  const int split = bid & 7;                 // consecutive bids -> XCD round-robin
  const int row0 = (bid >> 3) * BM;
  const int ks = split * KSLICE;

  // W tile: [comp(2)][slot(4)][n(128)][8 halves] = 16 KB
  __shared__ _Float16 wtile[8192];
  // x tile: [2][32 rows][144 B] = 9216 B
  __shared__ char xbuf[2][BM * XROWB];

  const int tid = threadIdx.x;
  const int lane = tid & 63;
  const int wn = tid >> 6;                   // wave = col quarter

  // W staging: 16 chunks of 1KB (comp,slot,nh), 4 per wave
  auto stageW = [&](int k0) {
#pragma unroll
    for (int c = 0; c < 4; ++c) {
      int ch = wn * 4 + c;
      int comp = ch >> 3, slot = (ch >> 1) & 3, nh = ch & 1;
      const _Float16* src = wt + (size_t)comp * NPAD * KT +
                            (size_t)(nh * 64 + lane) * KT + k0 + slot * 8;
      gload_lds16((const void*)src, (void*)&wtile[((comp * 4 + slot) * 128 + nh * 64) * 8]);
    }
  };

  // x load (regs): thread -> (row = tid>>3, 4 floats at kq = tid&7)
  const int xrow = tid >> 3;
  const int xkq = (tid & 7) * 4;
  const float* xrp = x + (size_t)(row0 + xrow) * KDIM;
  float2 xv0, xv1;
  auto loadX = [&](int t) {
    int k = ks + t * BK + xkq;
    if (k + 4 <= KDIM) {
      xv0 = *(const float2*)(xrp + k);
      xv1 = *(const float2*)(xrp + k + 2);
    } else {
      xv0.x = (k     < KDIM) ? xrp[k]     : 0.f;
      xv0.y = (k + 1 < KDIM) ? xrp[k + 1] : 0.f;
      xv1.x = (k + 2 < KDIM) ? xrp[k + 2] : 0.f;
      xv1.y = (k + 3 < KDIM) ? xrp[k + 3] : 0.f;
    }
  };
  auto writeX = [&](int buf) {
    *(float4*)(xbuf[buf] + xrow * XROWB + xkq * 4) = make_float4(xv0.x, xv0.y, xv1.x, xv1.y);
  };

  f32x16 accA = (f32x16)(0.f), accB = (f32x16)(0.f);
  const int arow = lane & 31;
  const int khalf = lane >> 5;
  const int col = wn * 32 + (lane & 31);

  // prologue
  stageW(ks);
  loadX(0);
  writeX(0);

  for (int t = 0; t < NITER; ++t) {
    const int cur = t & 1;
    asm volatile("s_waitcnt vmcnt(0) lgkmcnt(0)" ::: "memory");
    __builtin_amdgcn_s_barrier();            // W(t) + x(t) visible

    if (t + 1 < NITER) loadX(t + 1);         // issue early (T14)

    // A fragments: fp32 from LDS -> hi/lo fp16
    half8 ah[2], al[2];
    {
      const char* ab = xbuf[cur] + arow * XROWB + khalf * 32;
#pragma unroll
      for (int ksub = 0; ksub < 2; ++ksub) {
        float4 f0 = *(const float4*)(ab + ksub * 64);
        float4 f1 = *(const float4*)(ab + ksub * 64 + 16);
        float f[8] = {f0.x, f0.y, f0.z, f0.w, f1.x, f1.y, f1.z, f1.w};
#pragma unroll
        for (int i = 0; i < 8; ++i) {
          _Float16 h = (_Float16)f[i];
          ah[ksub][i] = h;
          al[ksub][i] = (_Float16)((f[i] - (float)h) * 2048.0f);
        }
      }
    }
    // B fragments (contiguous across lanes, conflict-free)
    half8 bh[2], bl[2];
#pragma unroll
    for (int ksub = 0; ksub < 2; ++ksub) {
      int slot = ksub * 2 + khalf;
      bh[ksub] = *(const half8*)&wtile[((0 * 4 + slot) * 128 + col) * 8];
      bl[ksub] = *(const half8*)&wtile[((1 * 4 + slot) * 128 + col) * 8];
    }

#pragma unroll
    for (int ksub = 0; ksub < 2; ++ksub) {
      accA = __builtin_amdgcn_mfma_f32_32x32x16_f16(ah[ksub], bh[ksub], accA, 0, 0, 0);
      accB = __builtin_amdgcn_mfma_f32_32x32x16_f16(al[ksub], bh[ksub], accB, 0, 0, 0);
      accB = __builtin_amdgcn_mfma_f32_32x32x16_f16(ah[ksub], bl[ksub], accB, 0, 0, 0);
    }

    if (t + 1 < NITER) writeX(cur ^ 1);      // write late (x regs retired by now)

    asm volatile("s_waitcnt lgkmcnt(0)" ::: "memory");
    __builtin_amdgcn_s_barrier();            // readers of wtile(t) done
    if (t + 1 < NITER) stageW(ks + (t + 1) * BK);
  }

  float* pb = partial + (size_t)split * BSZ * NPAD;
#pragma unroll
  for (int r = 0; r < 16; ++r) {
    int row = row0 + (r & 3) + 8 * (r >> 2) + 4 * khalf;
    pb[(size_t)row * NPAD + col] = accA[r] + accB[r] * (1.0f / 2048.0f);
  }
}

// ---------------- fused reduce + epilogue (coalesced via LDS)
__device__ __forceinline__ void axis_mask(const float a[WD], int lo, int hi, float m[WD]) {
  float am[WD];
  float tot = 0.f;
#pragma unroll
  for (int c = 0; c < WD; ++c) { am[c] = (c >= lo) ? a[c] : 0.f; tot += am[c]; }
  float run = 0.f;
  float c1[WD];
#pragma unroll
  for (int c = 0; c < WD; ++c) {
    run += am[c] / tot;
    c1[c] = (run >= 0.3f) ? run : 0.f;
  }
  float tot2 = 0.f;
#pragma unroll
  for (int c = 0; c < WD; ++c) { am[c] = (c < hi) ? a[c] : 0.f; tot2 += am[c]; }
  run = 0.f;
#pragma unroll
  for (int c = 0; c < WD; ++c) {
    run += am[c] / tot2;
    float c2 = 1.f - run;
    c2 = (c2 >= 0.3f) ? c2 : 0.f;
    m[c] = c1[c] * c2;
  }
}

__global__ __launch_bounds__(256) void epi_kernel(const char* __restrict__ wsb,
                                                  const float* __restrict__ keypoint,
                                                  float* __restrict__ out) {
  __shared__ float vlds[64][132];            // pad 4 floats
  const int b0 = blockIdx.x * 64;
  const int tid = threadIdx.x;
  const float4* part4 = (const float4*)(wsb + OFF_PART);
  const float4* bias4 = (const float4*)(wsb + OFF_BIAS);

  // phase 1: coalesced splitK reduce into LDS (order: sp ascending, bias last)
  float4 a[8];
#pragma unroll
  for (int j = 0; j < 8; ++j) {
    int fi = tid * 8 + j;                    // 0..2047 ; r = fi>>5, c4 = fi&31
    a[j] = part4[((size_t)(b0 + (fi >> 5))) * 32 + (fi & 31)];
  }
  for (int sp = 1; sp < SPLITK; ++sp) {
#pragma unroll
    for (int j = 0; j < 8; ++j) {
      int fi = tid * 8 + j;
      float4 p = part4[((size_t)sp * BSZ + b0 + (fi >> 5)) * 32 + (fi & 31)];
      a[j].x += p.x; a[j].y += p.y; a[j].z += p.z; a[j].w += p.w;
    }
  }
#pragma unroll
  for (int j = 0; j < 8; ++j) {
    int fi = tid * 8 + j;
    float4 bb = bias4[fi & 31];
    a[j].x += bb.x; a[j].y += bb.y; a[j].z += bb.z; a[j].w += bb.w;
    *(float4*)&vlds[fi >> 5][(fi & 31) * 4] = a[j];
  }
  __syncthreads();

  // phase 2: per-(sample,family) math
  for (int u = tid; u < 64 * 5; u += 256) {
    int fam = u >> 6;
    int bl = u & 63;
    int b = b0 + bl;
    const int G = (fam == 4) ? 1 : 2;
    const int nk = (fam == 4) ? 2 : 4;
    const float* vv = &vlds[bl][fam * 28];

    int mnx = 7, mxx = -1, mny = 7, mxy = -1;
    for (int i = 0; i < nk; ++i) {
      int kidx = KIDX[fam][i];
      float fx = keypoint[((size_t)b * 17 + kidx) * 2 + 0];
      float fy = keypoint[((size_t)b * 17 + kidx) * 2 + 1];
      int ix = (int)floorf(fx * 7.0f); ix = ix < 6 ? ix : 6;
      int iy = (int)floorf(fy * 7.0f); iy = iy < 6 ? iy : 6;
      mnx = min(mnx, ix); mxx = max(mxx, ix);
      mny = min(mny, iy); mxy = max(mxy, iy);
    }
    int lox = mnx - 1; if (lox < 0) lox = 0;
    int hix = mxx + 1; if (hix > 6) hix = 6;
    int loy = mny - 1; if (loy < 0) loy = 0;
    int hiy = mxy + 1; if (hiy > 6) hiy = 6;

    float xmg[2][WD], ymg[2][WD];
    float mx = 0.f;
#pragma unroll
    for (int g = 0; g < 2; ++g) {
      if (g < G) {
        const float* vg = vv + g * 14;
        float a0[WD], a1[WD];
#pragma unroll
        for (int c = 0; c < WD; ++c) {
          float s0 = vg[c], s1 = vg[c + 7];
          float mM = fmaxf(s0, s1);
          float e0 = expf(s0 - mM), e1 = expf(s1 - mM);
          float sum = e0 + e1;
          a0[c] = expf(e0 / sum);
          a1[c] = expf(e1 / sum);
        }
        axis_mask(a0, lox, hix, xmg[g]);
        axis_mask(a1, loy, hiy, ymg[g]);
        float mx_x = 0.f, mx_y = 0.f;
#pragma unroll
        for (int c = 0; c < WD; ++c) {
          mx_x = fmaxf(mx_x, xmg[g][c]);
          mx_y = fmaxf(mx_y, ymg[g][c]);
        }
        mx = fmaxf(mx, mx_y * mx_x);
      }
    }

    float d = mx + 1e-7f;
    float* op = out + OBASE[fam] + (size_t)b * (G * 49);
#pragma unroll
    for (int g = 0; g < 2; ++g) {
      if (g < G) {
#pragma unroll
        for (int y = 0; y < WD; ++y) {
          float yv = ymg[g][y];
#pragma unroll
          for (int xx = 0; xx < WD; ++xx) {
            op[g * 49 + y * 7 + xx] = (yv * xmg[g][xx]) / d;
          }
        }
      }
    }
  }
}

extern "C" void kernel_launch(void* const* d_in, const int* in_sizes, int n_in,
                              void* d_out, int out_size, void* d_ws, size_t ws_size,
                              hipStream_t stream) {
  const float* x        = (const float*)d_in[0];
  const float* keypoint = (const float*)d_in[1];
  const float* Wh = (const float*)d_in[2];
  const float* bh = (const float*)d_in[3];
  const float* Wa = (const float*)d_in[4];
  const float* ba = (const float*)d_in[5];
  const float* Wu = (const float*)d_in[6];
  const float* bu = (const float*)d_in[7];
  const float* Wl = (const float*)d_in[8];
  const float* bl = (const float*)d_in[9];
  const float* Wf = (const float*)d_in[10];
  const float* bf = (const float*)d_in[11];
  float* out = (float*)d_out;
  char* wsb  = (char*)d_ws;

  hipLaunchKernelGGL(pack_kernel, dim3(KT / 64), dim3(256), 0, stream,
                     Wh, bh, Wa, ba, Wu, bu, Wl, bl, Wf, bf, wsb);
  hipLaunchKernelGGL(gemm_kernel, dim3((BSZ / BM) * SPLITK), dim3(256), 0, stream, x, wsb);
  hipLaunchKernelGGL(epi_kernel, dim3(BSZ / 64), dim3(256), 0, stream,
                     wsb, keypoint, out);
}